// Round 13
// baseline (72.646 us; speedup 1.0000x reference)
//
#include <hip/hip_runtime.h>
#include <hip/hip_fp16.h>
#include <stdint.h>

#define BATCH   1024
#define IDIM    4096
#define NLUTS   16384

// ---- main kernel geometry (R10's best: 39.2 us) ----
#define TPB     1024
#define NT      2                    // n's per thread per chunk
#define NPB     (TPB * NT)           // 2048
#define CH      2                    // chunks per sweep
#define NSWEEP  (NPB * CH)           // 4096 n per block
#define NBLK_N  (NLUTS / NSWEEP)     // 4
#define BT      8                    // rows per LDS tile (fp16 -> b128 = 8 rows)
#define TILES   2
#define ROWS    (BT * TILES)         // 16 rows per block
#define NBLK_B  (BATCH / ROWS)       // 64
#define GRID    (NBLK_N * NBLK_B)    // 256

typedef float f32x2 __attribute__((ext_vector_type(2)));   // native vec for nt-store

// ---------------- coefficient pre-kernel (f32, R10's) ----------------
__global__ __launch_bounds__(256, 4)
void coeff_kernel(const float* __restrict__ w,
                  const float* __restrict__ wc,
                  float* __restrict__ cf)
{
    int n = blockIdx.x * 256 + threadIdx.x;   // grid = 64 x 256
    float p[16];
#pragma unroll
    for (int k = 0; k < 4; ++k) {
        float4 wv = *reinterpret_cast<const float4*>(w  + (size_t)n * 16 + 4 * k);
        float4 cv = *reinterpret_cast<const float4*>(wc + (size_t)n * 16 + 4 * k);
        p[15 - (4 * k + 0)] = 1.f / (1.f + __expf(cv.x - wv.x));
        p[15 - (4 * k + 1)] = 1.f / (1.f + __expf(cv.y - wv.y));
        p[15 - (4 * k + 2)] = 1.f / (1.f + __expf(cv.z - wv.z));
        p[15 - (4 * k + 3)] = 1.f / (1.f + __expf(cv.w - wv.w));
    }
#pragma unroll
    for (int s = 8; s >= 1; s >>= 1) {
#pragma unroll
        for (int m = 0; m < 16; ++m) {
            if ((m & s) == 0) { float t0 = p[m]; p[m] = p[m + s]; p[m + s] = t0 - p[m + s]; }
        }
    }
#pragma unroll
    for (int k = 0; k < 4; ++k) {
        float4 o; o.x = p[4*k]; o.y = p[4*k+1]; o.z = p[4*k+2]; o.w = p[4*k+3];
        *reinterpret_cast<float4*>(cf + (size_t)n * 16 + 4 * k) = o;
    }
}

// ---------------- main kernel ----------------
// R10 structure + latency-chain cuts: idx fully hoisted to prologue (gathers
// have zero in-phase global dependency), cf loads overlap gathers, out
// stores nontemporal (don't evict x/cf/idx from L2).
__global__ __launch_bounds__(TPB, 2)
void lut_main(const float* __restrict__ x,
              const float* __restrict__ cf,
              const int*   __restrict__ indices,
              float* __restrict__ out)
{
    // transposed fp16 tile: xt[col*8 + r] = x[brow+r][col]. 64 KB.
    __shared__ __half xt[IDIM * BT];

    // XCD swizzle: 4 n-blocks sharing a b-range consecutive on one XCD.
    int id    = blockIdx.x;
    int xcd   = id & 7;
    int k     = id >> 3;               // 0..31
    int n_blk = k & (NBLK_N - 1);      // 0..3, fastest
    int b_blk = (k >> 2) * 8 + xcd;    // 0..63, bijective
    int t     = threadIdx.x;
    int b0    = b_blk * ROWS;
    int nbase = n_blk * NSWEEP;

    const char* xt_bytes = reinterpret_cast<const char*>(xt);

    // ---- prologue: hoist ALL idx loads (both chunks; tiles share n) ----
    // off_all[c][q][i]: LDS byte offset of column indices[i][n0(c)+q].
    uint32_t off_all[CH][NT][4];
#pragma unroll
    for (int c = 0; c < CH; ++c) {
        int n0 = nbase + c * NPB + t * NT;
#pragma unroll
        for (int i = 0; i < 4; ++i) {
            int2 v = *reinterpret_cast<const int2*>(indices + (size_t)i * NLUTS + n0);
            off_all[c][0][i] = (uint32_t)v.x * 16u;
            off_all[c][1][i] = (uint32_t)v.y * 16u;
        }
    }

    // stage 8 rows: thread owns cols 4t..4t+3 (R10's proven pattern).
    auto stage = [&](int g) {
        const float* xb = x + (size_t)(b0 + g * BT) * IDIM + 4 * t;
        float4 rr[BT];
#pragma unroll
        for (int r = 0; r < BT; ++r)
            rr[r] = *reinterpret_cast<const float4*>(xb + (size_t)r * IDIM);
#pragma unroll
        for (int j = 0; j < 4; ++j) {
            float c0 = reinterpret_cast<const float*>(&rr[0])[j];
            float c1 = reinterpret_cast<const float*>(&rr[1])[j];
            float c2 = reinterpret_cast<const float*>(&rr[2])[j];
            float c3 = reinterpret_cast<const float*>(&rr[3])[j];
            float c4 = reinterpret_cast<const float*>(&rr[4])[j];
            float c5 = reinterpret_cast<const float*>(&rr[5])[j];
            float c6 = reinterpret_cast<const float*>(&rr[6])[j];
            float c7 = reinterpret_cast<const float*>(&rr[7])[j];
            __half2 h01 = __floats2half2_rn(c0, c1);
            __half2 h23 = __floats2half2_rn(c2, c3);
            __half2 h45 = __floats2half2_rn(c4, c5);
            __half2 h67 = __floats2half2_rn(c6, c7);
            uint4 v;
            v.x = *reinterpret_cast<uint32_t*>(&h01);
            v.y = *reinterpret_cast<uint32_t*>(&h23);
            v.z = *reinterpret_cast<uint32_t*>(&h45);
            v.w = *reinterpret_cast<uint32_t*>(&h67);
            *reinterpret_cast<uint4*>(&xt[(size_t)(4 * t + j) * 8]) = v;
        }
    };

    // one (tile, chunk) phase: cf loads issue FIRST (overlap the gathers),
    // gathers issue immediately from pre-hoisted offsets, then FMA + nt-store.
    auto phase = [&](int g, int c) {
        int n0 = nbase + c * NPB + t * NT;

        // cf loads (independent of gathers -> in flight together)
        float a[NT][16];
#pragma unroll
        for (int q = 0; q < NT; ++q) {
#pragma unroll
            for (int kk = 0; kk < 4; ++kk) {
                float4 v = *reinterpret_cast<const float4*>(cf + (size_t)(n0 + q) * 16 + 4 * kk);
                a[q][4*kk] = v.x; a[q][4*kk+1] = v.y; a[q][4*kk+2] = v.z; a[q][4*kk+3] = v.w;
            }
        }

        float res[NT][BT];
#pragma unroll
        for (int q = 0; q < NT; ++q) {
            uint4 gld[4];
#pragma unroll
            for (int i = 0; i < 4; ++i)
                gld[i] = *reinterpret_cast<const uint4*>(xt_bytes + off_all[c][q][i]);

            float cc[4][BT];
#pragma unroll
            for (int i = 0; i < 4; ++i) {
                __half2 h01 = *reinterpret_cast<__half2*>(&gld[i].x);
                __half2 h23 = *reinterpret_cast<__half2*>(&gld[i].y);
                __half2 h45 = *reinterpret_cast<__half2*>(&gld[i].z);
                __half2 h67 = *reinterpret_cast<__half2*>(&gld[i].w);
                float2 f01 = __half22float2(h01);
                float2 f23 = __half22float2(h23);
                float2 f45 = __half22float2(h45);
                float2 f67 = __half22float2(h67);
                cc[i][0] = f01.x; cc[i][1] = f01.y; cc[i][2] = f23.x; cc[i][3] = f23.y;
                cc[i][4] = f45.x; cc[i][5] = f45.y; cc[i][6] = f67.x; cc[i][7] = f67.y;
            }
#pragma unroll
            for (int r = 0; r < BT; ++r) {
                float v0 = cc[0][r], v1 = cc[1][r], v2 = cc[2][r], v3 = cc[3][r];
                float h0 = fmaf(v3, a[q][1],  a[q][0]);
                float h1 = fmaf(v3, a[q][3],  a[q][2]);
                float h2 = fmaf(v3, a[q][5],  a[q][4]);
                float h3 = fmaf(v3, a[q][7],  a[q][6]);
                float h4 = fmaf(v3, a[q][9],  a[q][8]);
                float h5 = fmaf(v3, a[q][11], a[q][10]);
                float h6 = fmaf(v3, a[q][13], a[q][12]);
                float h7 = fmaf(v3, a[q][15], a[q][14]);
                float g0 = fmaf(v2, h1, h0);
                float g1 = fmaf(v2, h3, h2);
                float g2 = fmaf(v2, h5, h4);
                float g3 = fmaf(v2, h7, h6);
                float f0 = fmaf(v1, g1, g0);
                float f1 = fmaf(v1, g3, g2);
                res[q][r] = fmaf(v0, f1, f0);
            }
        }

        // nontemporal stores (native ext_vector type): out is never re-read.
#pragma unroll
        for (int r = 0; r < BT; ++r) {
            f32x2 o; o.x = res[0][r]; o.y = res[1][r];
            __builtin_nontemporal_store(
                o, reinterpret_cast<f32x2*>(out + (size_t)(b0 + g * BT + r) * NLUTS + n0));
        }
    };

    stage(0);
    __syncthreads();
    phase(0, 0);
    phase(0, 1);
    __syncthreads();           // all reads of tile 0 done
    stage(1);
    __syncthreads();
    phase(1, 0);
    phase(1, 1);
}

// ---------------- fallback (round-1 fused kernel, used only if ws too small) ----------------
#define F_TPB   256
#define F_NT    4
#define F_NPB   (F_TPB * F_NT)
#define F_NBLKN (NLUTS / F_NPB)
#define F_BTILE 16
#define F_GRID  (F_NBLKN * (BATCH / F_BTILE))

__global__ __launch_bounds__(F_TPB, 4)
void lut_fused(const float* __restrict__ x, const float* __restrict__ w,
               const float* __restrict__ wcomp, const int* __restrict__ indices,
               float* __restrict__ out)
{
    __shared__ float xsf[2][IDIM];
    int id = blockIdx.x;
    int swz = (id & 7) * (F_GRID / 8) + (id >> 3);
    int b_blk = swz / F_NBLKN, n_blk = swz % F_NBLKN;
    int t = threadIdx.x;
    int n0 = n_blk * F_NPB + t * F_NT;
    int b0 = b_blk * F_BTILE;
    int ix[F_NT][4];
#pragma unroll
    for (int i = 0; i < 4; ++i) {
        int4 v = *reinterpret_cast<const int4*>(indices + i * NLUTS + n0);
        ix[0][i] = v.x; ix[1][i] = v.y; ix[2][i] = v.z; ix[3][i] = v.w;
    }
    float a[F_NT][16];
#pragma unroll
    for (int q = 0; q < F_NT; ++q) {
        int n = n0 + q; float p[16];
#pragma unroll
        for (int k = 0; k < 4; ++k) {
            float4 wv = *reinterpret_cast<const float4*>(w     + (size_t)n * 16 + k * 4);
            float4 cv = *reinterpret_cast<const float4*>(wcomp + (size_t)n * 16 + k * 4);
            p[15-(4*k+0)] = 1.f/(1.f+__expf(cv.x-wv.x));
            p[15-(4*k+1)] = 1.f/(1.f+__expf(cv.y-wv.y));
            p[15-(4*k+2)] = 1.f/(1.f+__expf(cv.z-wv.z));
            p[15-(4*k+3)] = 1.f/(1.f+__expf(cv.w-wv.w));
        }
#pragma unroll
        for (int s = 8; s >= 1; s >>= 1)
#pragma unroll
            for (int m = 0; m < 16; ++m)
                if ((m & s) == 0) { float t0 = p[m]; p[m] = p[m+s]; p[m+s] = t0 - p[m+s]; }
#pragma unroll
        for (int m = 0; m < 16; ++m) a[q][m] = p[m];
    }
    {
        const float* xrow = x + (size_t)b0 * IDIM;
#pragma unroll
        for (int k = 0; k < 4; ++k)
            *reinterpret_cast<float4*>(&xsf[0][(k*F_TPB+t)*4]) =
                *reinterpret_cast<const float4*>(xrow + (k*F_TPB+t)*4);
    }
    __syncthreads();
    for (int bi = 0; bi < F_BTILE; ++bi) {
        int cur = bi & 1; bool more = (bi + 1 < F_BTILE);
        float4 r[4];
        if (more) {
            const float* xrow = x + (size_t)(b0+bi+1) * IDIM;
#pragma unroll
            for (int k = 0; k < 4; ++k)
                r[k] = *reinterpret_cast<const float4*>(xrow + (k*F_TPB+t)*4);
        }
        float res[F_NT];
#pragma unroll
        for (int q = 0; q < F_NT; ++q) {
            float v0 = xsf[cur][ix[q][0]], v1 = xsf[cur][ix[q][1]];
            float v2 = xsf[cur][ix[q][2]], v3 = xsf[cur][ix[q][3]];
            float h0 = fmaf(v3,a[q][1],a[q][0]),  h1 = fmaf(v3,a[q][3],a[q][2]);
            float h2 = fmaf(v3,a[q][5],a[q][4]),  h3 = fmaf(v3,a[q][7],a[q][6]);
            float h4 = fmaf(v3,a[q][9],a[q][8]),  h5 = fmaf(v3,a[q][11],a[q][10]);
            float h6 = fmaf(v3,a[q][13],a[q][12]),h7 = fmaf(v3,a[q][15],a[q][14]);
            float g0 = fmaf(v2,h1,h0), g1 = fmaf(v2,h3,h2);
            float g2 = fmaf(v2,h5,h4), g3 = fmaf(v2,h7,h6);
            res[q] = fmaf(v0, fmaf(v1,g3,g2), fmaf(v1,g1,g0));
        }
        float4 o; o.x=res[0]; o.y=res[1]; o.z=res[2]; o.w=res[3];
        *reinterpret_cast<float4*>(out + (size_t)(b0+bi)*NLUTS + n0) = o;
        if (more) {
            int nxt = cur ^ 1;
#pragma unroll
            for (int k = 0; k < 4; ++k)
                *reinterpret_cast<float4*>(&xsf[nxt][(k*F_TPB+t)*4]) = r[k];
        }
        __syncthreads();
    }
}

extern "C" void kernel_launch(void* const* d_in, const int* in_sizes, int n_in,
                              void* d_out, int out_size, void* d_ws, size_t ws_size,
                              hipStream_t stream) {
    const float* x   = (const float*)d_in[0];
    const float* w   = (const float*)d_in[1];
    const float* wc  = (const float*)d_in[2];
    const int*   idx = (const int*)d_in[3];
    float*       out = (float*)d_out;

    if (ws_size >= (size_t)NLUTS * 16 * sizeof(float)) {
        float* cf = (float*)d_ws;
        coeff_kernel<<<dim3(NLUTS / 256), dim3(256), 0, stream>>>(w, wc, cf);
        lut_main<<<dim3(GRID), dim3(TPB), 0, stream>>>(x, cf, idx, out);
    } else {
        lut_fused<<<dim3(F_GRID), dim3(F_TPB), 0, stream>>>(x, w, wc, idx, out);
    }
}

// Round 14
// 71.571 us; speedup vs baseline: 1.0150x; 1.0150x over previous
//
#include <hip/hip_runtime.h>
#include <hip/hip_fp16.h>
#include <stdint.h>

#define BATCH   1024
#define IDIM    4096
#define NLUTS   16384

// ---- main kernel geometry (R10's best: 39.2 us) ----
#define TPB     1024
#define NT      2                    // n's per thread per chunk
#define NPB     (TPB * NT)           // 2048
#define CH      2                    // chunks per sweep
#define NSWEEP  (NPB * CH)           // 4096 n per block
#define NBLK_N  (NLUTS / NSWEEP)     // 4
#define BT      8                    // rows per LDS tile (fp16 -> b128 = 8 rows)
#define TILES   2
#define ROWS    (BT * TILES)         // 16 rows per block
#define NBLK_B  (BATCH / ROWS)       // 64
#define GRID    (NBLK_N * NBLK_B)    // 256

// ---------------- coefficient pre-kernel (f32, R10's) ----------------
__global__ __launch_bounds__(256, 4)
void coeff_kernel(const float* __restrict__ w,
                  const float* __restrict__ wc,
                  float* __restrict__ cf)
{
    int n = blockIdx.x * 256 + threadIdx.x;   // grid = 64 x 256
    float p[16];
#pragma unroll
    for (int k = 0; k < 4; ++k) {
        float4 wv = *reinterpret_cast<const float4*>(w  + (size_t)n * 16 + 4 * k);
        float4 cv = *reinterpret_cast<const float4*>(wc + (size_t)n * 16 + 4 * k);
        p[15 - (4 * k + 0)] = 1.f / (1.f + __expf(cv.x - wv.x));
        p[15 - (4 * k + 1)] = 1.f / (1.f + __expf(cv.y - wv.y));
        p[15 - (4 * k + 2)] = 1.f / (1.f + __expf(cv.z - wv.z));
        p[15 - (4 * k + 3)] = 1.f / (1.f + __expf(cv.w - wv.w));
    }
#pragma unroll
    for (int s = 8; s >= 1; s >>= 1) {
#pragma unroll
        for (int m = 0; m < 16; ++m) {
            if ((m & s) == 0) { float t0 = p[m]; p[m] = p[m + s]; p[m + s] = t0 - p[m + s]; }
        }
    }
#pragma unroll
    for (int k = 0; k < 4; ++k) {
        float4 o; o.x = p[4*k]; o.y = p[4*k+1]; o.z = p[4*k+2]; o.w = p[4*k+3];
        *reinterpret_cast<float4*>(cf + (size_t)n * 16 + 4 * k) = o;
    }
}

// ---------------- main kernel ----------------
// R10 structure + latency-chain cuts (idx fully hoisted, cf loads issued
// ahead of gathers). Plain stores — R13 proved 8B nontemporal stores
// write-amplify 3x on gfx950 (WRITE_SIZE 64->193 MB).
__global__ __launch_bounds__(TPB, 2)
void lut_main(const float* __restrict__ x,
              const float* __restrict__ cf,
              const int*   __restrict__ indices,
              float* __restrict__ out)
{
    // transposed fp16 tile: xt[col*8 + r] = x[brow+r][col]. 64 KB.
    __shared__ __half xt[IDIM * BT];

    // XCD swizzle: 4 n-blocks sharing a b-range consecutive on one XCD.
    int id    = blockIdx.x;
    int xcd   = id & 7;
    int k     = id >> 3;               // 0..31
    int n_blk = k & (NBLK_N - 1);      // 0..3, fastest
    int b_blk = (k >> 2) * 8 + xcd;    // 0..63, bijective
    int t     = threadIdx.x;
    int b0    = b_blk * ROWS;
    int nbase = n_blk * NSWEEP;

    const char* xt_bytes = reinterpret_cast<const char*>(xt);

    // ---- prologue: hoist ALL idx loads (both chunks; tiles share n) ----
    uint32_t off_all[CH][NT][4];
#pragma unroll
    for (int c = 0; c < CH; ++c) {
        int n0 = nbase + c * NPB + t * NT;
#pragma unroll
        for (int i = 0; i < 4; ++i) {
            int2 v = *reinterpret_cast<const int2*>(indices + (size_t)i * NLUTS + n0);
            off_all[c][0][i] = (uint32_t)v.x * 16u;
            off_all[c][1][i] = (uint32_t)v.y * 16u;
        }
    }

    // stage 8 rows: thread owns cols 4t..4t+3 (R10's proven pattern).
    auto stage = [&](int g) {
        const float* xb = x + (size_t)(b0 + g * BT) * IDIM + 4 * t;
        float4 rr[BT];
#pragma unroll
        for (int r = 0; r < BT; ++r)
            rr[r] = *reinterpret_cast<const float4*>(xb + (size_t)r * IDIM);
#pragma unroll
        for (int j = 0; j < 4; ++j) {
            float c0 = reinterpret_cast<const float*>(&rr[0])[j];
            float c1 = reinterpret_cast<const float*>(&rr[1])[j];
            float c2 = reinterpret_cast<const float*>(&rr[2])[j];
            float c3 = reinterpret_cast<const float*>(&rr[3])[j];
            float c4 = reinterpret_cast<const float*>(&rr[4])[j];
            float c5 = reinterpret_cast<const float*>(&rr[5])[j];
            float c6 = reinterpret_cast<const float*>(&rr[6])[j];
            float c7 = reinterpret_cast<const float*>(&rr[7])[j];
            __half2 h01 = __floats2half2_rn(c0, c1);
            __half2 h23 = __floats2half2_rn(c2, c3);
            __half2 h45 = __floats2half2_rn(c4, c5);
            __half2 h67 = __floats2half2_rn(c6, c7);
            uint4 v;
            v.x = *reinterpret_cast<uint32_t*>(&h01);
            v.y = *reinterpret_cast<uint32_t*>(&h23);
            v.z = *reinterpret_cast<uint32_t*>(&h45);
            v.w = *reinterpret_cast<uint32_t*>(&h67);
            *reinterpret_cast<uint4*>(&xt[(size_t)(4 * t + j) * 8]) = v;
        }
    };

    // one (tile, chunk) phase: cf loads issue FIRST (overlap the gathers),
    // gathers issue immediately from pre-hoisted offsets, then FMA + store.
    auto phase = [&](int g, int c) {
        int n0 = nbase + c * NPB + t * NT;

        // cf loads (independent of gathers -> in flight together)
        float a[NT][16];
#pragma unroll
        for (int q = 0; q < NT; ++q) {
#pragma unroll
            for (int kk = 0; kk < 4; ++kk) {
                float4 v = *reinterpret_cast<const float4*>(cf + (size_t)(n0 + q) * 16 + 4 * kk);
                a[q][4*kk] = v.x; a[q][4*kk+1] = v.y; a[q][4*kk+2] = v.z; a[q][4*kk+3] = v.w;
            }
        }

        float res[NT][BT];
#pragma unroll
        for (int q = 0; q < NT; ++q) {
            uint4 gld[4];
#pragma unroll
            for (int i = 0; i < 4; ++i)
                gld[i] = *reinterpret_cast<const uint4*>(xt_bytes + off_all[c][q][i]);

            float cc[4][BT];
#pragma unroll
            for (int i = 0; i < 4; ++i) {
                __half2 h01 = *reinterpret_cast<__half2*>(&gld[i].x);
                __half2 h23 = *reinterpret_cast<__half2*>(&gld[i].y);
                __half2 h45 = *reinterpret_cast<__half2*>(&gld[i].z);
                __half2 h67 = *reinterpret_cast<__half2*>(&gld[i].w);
                float2 f01 = __half22float2(h01);
                float2 f23 = __half22float2(h23);
                float2 f45 = __half22float2(h45);
                float2 f67 = __half22float2(h67);
                cc[i][0] = f01.x; cc[i][1] = f01.y; cc[i][2] = f23.x; cc[i][3] = f23.y;
                cc[i][4] = f45.x; cc[i][5] = f45.y; cc[i][6] = f67.x; cc[i][7] = f67.y;
            }
#pragma unroll
            for (int r = 0; r < BT; ++r) {
                float v0 = cc[0][r], v1 = cc[1][r], v2 = cc[2][r], v3 = cc[3][r];
                float h0 = fmaf(v3, a[q][1],  a[q][0]);
                float h1 = fmaf(v3, a[q][3],  a[q][2]);
                float h2 = fmaf(v3, a[q][5],  a[q][4]);
                float h3 = fmaf(v3, a[q][7],  a[q][6]);
                float h4 = fmaf(v3, a[q][9],  a[q][8]);
                float h5 = fmaf(v3, a[q][11], a[q][10]);
                float h6 = fmaf(v3, a[q][13], a[q][12]);
                float h7 = fmaf(v3, a[q][15], a[q][14]);
                float g0 = fmaf(v2, h1, h0);
                float g1 = fmaf(v2, h3, h2);
                float g2 = fmaf(v2, h5, h4);
                float g3 = fmaf(v2, h7, h6);
                float f0 = fmaf(v1, g1, g0);
                float f1 = fmaf(v1, g3, g2);
                res[q][r] = fmaf(v0, f1, f0);
            }
        }

        // plain coalesced float2 stores (L2 write-combined)
#pragma unroll
        for (int r = 0; r < BT; ++r) {
            float2 o; o.x = res[0][r]; o.y = res[1][r];
            *reinterpret_cast<float2*>(out + (size_t)(b0 + g * BT + r) * NLUTS + n0) = o;
        }
    };

    stage(0);
    __syncthreads();
    phase(0, 0);
    phase(0, 1);
    __syncthreads();           // all reads of tile 0 done
    stage(1);
    __syncthreads();
    phase(1, 0);
    phase(1, 1);
}

// ---------------- fallback (round-1 fused kernel, used only if ws too small) ----------------
#define F_TPB   256
#define F_NT    4
#define F_NPB   (F_TPB * F_NT)
#define F_NBLKN (NLUTS / F_NPB)
#define F_BTILE 16
#define F_GRID  (F_NBLKN * (BATCH / F_BTILE))

__global__ __launch_bounds__(F_TPB, 4)
void lut_fused(const float* __restrict__ x, const float* __restrict__ w,
               const float* __restrict__ wcomp, const int* __restrict__ indices,
               float* __restrict__ out)
{
    __shared__ float xsf[2][IDIM];
    int id = blockIdx.x;
    int swz = (id & 7) * (F_GRID / 8) + (id >> 3);
    int b_blk = swz / F_NBLKN, n_blk = swz % F_NBLKN;
    int t = threadIdx.x;
    int n0 = n_blk * F_NPB + t * F_NT;
    int b0 = b_blk * F_BTILE;
    int ix[F_NT][4];
#pragma unroll
    for (int i = 0; i < 4; ++i) {
        int4 v = *reinterpret_cast<const int4*>(indices + i * NLUTS + n0);
        ix[0][i] = v.x; ix[1][i] = v.y; ix[2][i] = v.z; ix[3][i] = v.w;
    }
    float a[F_NT][16];
#pragma unroll
    for (int q = 0; q < F_NT; ++q) {
        int n = n0 + q; float p[16];
#pragma unroll
        for (int k = 0; k < 4; ++k) {
            float4 wv = *reinterpret_cast<const float4*>(w     + (size_t)n * 16 + k * 4);
            float4 cv = *reinterpret_cast<const float4*>(wcomp + (size_t)n * 16 + k * 4);
            p[15-(4*k+0)] = 1.f/(1.f+__expf(cv.x-wv.x));
            p[15-(4*k+1)] = 1.f/(1.f+__expf(cv.y-wv.y));
            p[15-(4*k+2)] = 1.f/(1.f+__expf(cv.z-wv.z));
            p[15-(4*k+3)] = 1.f/(1.f+__expf(cv.w-wv.w));
        }
#pragma unroll
        for (int s = 8; s >= 1; s >>= 1)
#pragma unroll
            for (int m = 0; m < 16; ++m)
                if ((m & s) == 0) { float t0 = p[m]; p[m] = p[m+s]; p[m+s] = t0 - p[m+s]; }
#pragma unroll
        for (int m = 0; m < 16; ++m) a[q][m] = p[m];
    }
    {
        const float* xrow = x + (size_t)b0 * IDIM;
#pragma unroll
        for (int k = 0; k < 4; ++k)
            *reinterpret_cast<float4*>(&xsf[0][(k*F_TPB+t)*4]) =
                *reinterpret_cast<const float4*>(xrow + (k*F_TPB+t)*4);
    }
    __syncthreads();
    for (int bi = 0; bi < F_BTILE; ++bi) {
        int cur = bi & 1; bool more = (bi + 1 < F_BTILE);
        float4 r[4];
        if (more) {
            const float* xrow = x + (size_t)(b0+bi+1) * IDIM;
#pragma unroll
            for (int k = 0; k < 4; ++k)
                r[k] = *reinterpret_cast<const float4*>(xrow + (k*F_TPB+t)*4);
        }
        float res[F_NT];
#pragma unroll
        for (int q = 0; q < F_NT; ++q) {
            float v0 = xsf[cur][ix[q][0]], v1 = xsf[cur][ix[q][1]];
            float v2 = xsf[cur][ix[q][2]], v3 = xsf[cur][ix[q][3]];
            float h0 = fmaf(v3,a[q][1],a[q][0]),  h1 = fmaf(v3,a[q][3],a[q][2]);
            float h2 = fmaf(v3,a[q][5],a[q][4]),  h3 = fmaf(v3,a[q][7],a[q][6]);
            float h4 = fmaf(v3,a[q][9],a[q][8]),  h5 = fmaf(v3,a[q][11],a[q][10]);
            float h6 = fmaf(v3,a[q][13],a[q][12]),h7 = fmaf(v3,a[q][15],a[q][14]);
            float g0 = fmaf(v2,h1,h0), g1 = fmaf(v2,h3,h2);
            float g2 = fmaf(v2,h5,h4), g3 = fmaf(v2,h7,h6);
            res[q] = fmaf(v0, fmaf(v1,g3,g2), fmaf(v1,g1,g0));
        }
        float4 o; o.x=res[0]; o.y=res[1]; o.z=res[2]; o.w=res[3];
        *reinterpret_cast<float4*>(out + (size_t)(b0+bi)*NLUTS + n0) = o;
        if (more) {
            int nxt = cur ^ 1;
#pragma unroll
            for (int k = 0; k < 4; ++k)
                *reinterpret_cast<float4*>(&xsf[nxt][(k*F_TPB+t)*4]) = r[k];
        }
        __syncthreads();
    }
}

extern "C" void kernel_launch(void* const* d_in, const int* in_sizes, int n_in,
                              void* d_out, int out_size, void* d_ws, size_t ws_size,
                              hipStream_t stream) {
    const float* x   = (const float*)d_in[0];
    const float* w   = (const float*)d_in[1];
    const float* wc  = (const float*)d_in[2];
    const int*   idx = (const int*)d_in[3];
    float*       out = (float*)d_out;

    if (ws_size >= (size_t)NLUTS * 16 * sizeof(float)) {
        float* cf = (float*)d_ws;
        coeff_kernel<<<dim3(NLUTS / 256), dim3(256), 0, stream>>>(w, wc, cf);
        lut_main<<<dim3(GRID), dim3(TPB), 0, stream>>>(x, cf, idx, out);
    } else {
        lut_fused<<<dim3(F_GRID), dim3(F_TPB), 0, stream>>>(x, w, wc, idx, out);
    }
}

// Round 15
// 39.079 us; speedup vs baseline: 1.8589x; 1.8314x over previous
//
#include <hip/hip_runtime.h>
#include <hip/hip_fp16.h>
#include <stdint.h>

#define BATCH   1024
#define IDIM    4096
#define NLUTS   16384

// ---- main kernel geometry (R10: best measured, 39.2 us) ----
#define TPB     1024
#define NT      2                    // n's per thread per chunk
#define NPB     (TPB * NT)           // 2048
#define CH      2                    // chunks per sweep
#define NSWEEP  (NPB * CH)           // 4096 n per block
#define NBLK_N  (NLUTS / NSWEEP)     // 4
#define BT      8                    // rows per LDS tile (fp16 -> b128 = 8 rows)
#define TILES   2
#define ROWS    (BT * TILES)         // 16 rows per block
#define NBLK_B  (BATCH / ROWS)       // 64
#define GRID    (NBLK_N * NBLK_B)    // 256 = 1 block per CU

// ---------------- coefficient pre-kernel ----------------
__global__ __launch_bounds__(256, 4)
void coeff_kernel(const float* __restrict__ w,
                  const float* __restrict__ wc,
                  float* __restrict__ cf)
{
    int n = blockIdx.x * 256 + threadIdx.x;   // grid = 64 x 256
    float p[16];
#pragma unroll
    for (int k = 0; k < 4; ++k) {
        float4 wv = *reinterpret_cast<const float4*>(w  + (size_t)n * 16 + 4 * k);
        float4 cv = *reinterpret_cast<const float4*>(wc + (size_t)n * 16 + 4 * k);
        p[15 - (4 * k + 0)] = 1.f / (1.f + __expf(cv.x - wv.x));
        p[15 - (4 * k + 1)] = 1.f / (1.f + __expf(cv.y - wv.y));
        p[15 - (4 * k + 2)] = 1.f / (1.f + __expf(cv.z - wv.z));
        p[15 - (4 * k + 3)] = 1.f / (1.f + __expf(cv.w - wv.w));
    }
#pragma unroll
    for (int s = 8; s >= 1; s >>= 1) {
#pragma unroll
        for (int m = 0; m < 16; ++m) {
            if ((m & s) == 0) { float t0 = p[m]; p[m] = p[m + s]; p[m + s] = t0 - p[m + s]; }
        }
    }
#pragma unroll
    for (int k = 0; k < 4; ++k) {
        float4 o; o.x = p[4*k]; o.y = p[4*k+1]; o.z = p[4*k+2]; o.w = p[4*k+3];
        *reinterpret_cast<float4*>(cf + (size_t)n * 16 + 4 * k) = o;
    }
}

// ---------------- main kernel (exact R10: per-phase idx loads keep live
// state within the 64-VGPR cap — hoisting spills ~128 MB scratch, R13/R14) ----
__global__ __launch_bounds__(TPB, 2)
void lut_main(const float* __restrict__ x,
              const float* __restrict__ cf,
              const int*   __restrict__ indices,
              float* __restrict__ out)
{
    // transposed fp16 tile: xt[col*8 + r] = x[brow+r][col]. 64 KB.
    __shared__ __half xt[IDIM * BT];

    // XCD swizzle: the 4 n-blocks sharing a b-range are consecutive on one
    // XCD -> staged x rows and cf slices L2-local.
    int id    = blockIdx.x;
    int xcd   = id & 7;
    int k     = id >> 3;               // 0..31
    int n_blk = k & (NBLK_N - 1);      // 0..3, fastest
    int b_blk = (k >> 2) * 8 + xcd;    // 0..63, bijective
    int t     = threadIdx.x;
    int b0    = b_blk * ROWS;
    int nbase = n_blk * NSWEEP;

    const char* xt_bytes = reinterpret_cast<const char*>(xt);

    // stage 8 rows: thread owns cols 4t..4t+3 (1024 threads x 4 cols = 4096).
    auto stage = [&](int g) {
        const float* xb = x + (size_t)(b0 + g * BT) * IDIM + 4 * t;
        float4 rr[BT];
#pragma unroll
        for (int r = 0; r < BT; ++r)
            rr[r] = *reinterpret_cast<const float4*>(xb + (size_t)r * IDIM);
#pragma unroll
        for (int j = 0; j < 4; ++j) {
            float c0 = reinterpret_cast<const float*>(&rr[0])[j];
            float c1 = reinterpret_cast<const float*>(&rr[1])[j];
            float c2 = reinterpret_cast<const float*>(&rr[2])[j];
            float c3 = reinterpret_cast<const float*>(&rr[3])[j];
            float c4 = reinterpret_cast<const float*>(&rr[4])[j];
            float c5 = reinterpret_cast<const float*>(&rr[5])[j];
            float c6 = reinterpret_cast<const float*>(&rr[6])[j];
            float c7 = reinterpret_cast<const float*>(&rr[7])[j];
            __half2 h01 = __floats2half2_rn(c0, c1);
            __half2 h23 = __floats2half2_rn(c2, c3);
            __half2 h45 = __floats2half2_rn(c4, c5);
            __half2 h67 = __floats2half2_rn(c6, c7);
            uint4 v;
            v.x = *reinterpret_cast<uint32_t*>(&h01);
            v.y = *reinterpret_cast<uint32_t*>(&h23);
            v.z = *reinterpret_cast<uint32_t*>(&h45);
            v.w = *reinterpret_cast<uint32_t*>(&h67);
            *reinterpret_cast<uint4*>(&xt[(size_t)(4 * t + j) * 8]) = v;
        }
    };

    // barrier-free sweep over this block's 4096 n for the staged 8 rows
    auto sweep = [&](int g) {
#pragma unroll 1
        for (int c = 0; c < CH; ++c) {
            int n0 = nbase + c * NPB + t * NT;

            uint32_t off[NT][4];
#pragma unroll
            for (int i = 0; i < 4; ++i) {
                int2 v = *reinterpret_cast<const int2*>(indices + i * NLUTS + n0);
                off[0][i] = (uint32_t)v.x * 16u;
                off[1][i] = (uint32_t)v.y * 16u;
            }

            float a[NT][16];
#pragma unroll
            for (int q = 0; q < NT; ++q) {
#pragma unroll
                for (int kk = 0; kk < 4; ++kk) {
                    float4 v = *reinterpret_cast<const float4*>(cf + (size_t)(n0 + q) * 16 + 4 * kk);
                    a[q][4*kk] = v.x; a[q][4*kk+1] = v.y; a[q][4*kk+2] = v.z; a[q][4*kk+3] = v.w;
                }
            }

            float res[NT][BT];
#pragma unroll
            for (int q = 0; q < NT; ++q) {
                uint4 gld[4];
#pragma unroll
                for (int i = 0; i < 4; ++i)
                    gld[i] = *reinterpret_cast<const uint4*>(xt_bytes + off[q][i]);

                float cc[4][BT];
#pragma unroll
                for (int i = 0; i < 4; ++i) {
                    __half2 h01 = *reinterpret_cast<__half2*>(&gld[i].x);
                    __half2 h23 = *reinterpret_cast<__half2*>(&gld[i].y);
                    __half2 h45 = *reinterpret_cast<__half2*>(&gld[i].z);
                    __half2 h67 = *reinterpret_cast<__half2*>(&gld[i].w);
                    float2 f01 = __half22float2(h01);
                    float2 f23 = __half22float2(h23);
                    float2 f45 = __half22float2(h45);
                    float2 f67 = __half22float2(h67);
                    cc[i][0] = f01.x; cc[i][1] = f01.y; cc[i][2] = f23.x; cc[i][3] = f23.y;
                    cc[i][4] = f45.x; cc[i][5] = f45.y; cc[i][6] = f67.x; cc[i][7] = f67.y;
                }
#pragma unroll
                for (int r = 0; r < BT; ++r) {
                    float v0 = cc[0][r], v1 = cc[1][r], v2 = cc[2][r], v3 = cc[3][r];
                    float h0 = fmaf(v3, a[q][1],  a[q][0]);
                    float h1 = fmaf(v3, a[q][3],  a[q][2]);
                    float h2 = fmaf(v3, a[q][5],  a[q][4]);
                    float h3 = fmaf(v3, a[q][7],  a[q][6]);
                    float h4 = fmaf(v3, a[q][9],  a[q][8]);
                    float h5 = fmaf(v3, a[q][11], a[q][10]);
                    float h6 = fmaf(v3, a[q][13], a[q][12]);
                    float h7 = fmaf(v3, a[q][15], a[q][14]);
                    float g0 = fmaf(v2, h1, h0);
                    float g1 = fmaf(v2, h3, h2);
                    float g2 = fmaf(v2, h5, h4);
                    float g3 = fmaf(v2, h7, h6);
                    float f0 = fmaf(v1, g1, g0);
                    float f1 = fmaf(v1, g3, g2);
                    res[q][r] = fmaf(v0, f1, f0);
                }
            }

            // coalesced float2 stores: 8 rows x (2 consecutive n per thread)
#pragma unroll
            for (int r = 0; r < BT; ++r) {
                float2 o; o.x = res[0][r]; o.y = res[1][r];
                *reinterpret_cast<float2*>(out + (size_t)(b0 + g * BT + r) * NLUTS + n0) = o;
            }
        }
    };

    stage(0);
    __syncthreads();
    sweep(0);
    __syncthreads();           // all reads of tile 0 done
    stage(1);
    __syncthreads();
    sweep(1);
}

// ---------------- fallback (round-1 fused kernel, used only if ws too small) ----------------
#define F_TPB   256
#define F_NT    4
#define F_NPB   (F_TPB * F_NT)
#define F_NBLKN (NLUTS / F_NPB)
#define F_BTILE 16
#define F_GRID  (F_NBLKN * (BATCH / F_BTILE))

__global__ __launch_bounds__(F_TPB, 4)
void lut_fused(const float* __restrict__ x, const float* __restrict__ w,
               const float* __restrict__ wcomp, const int* __restrict__ indices,
               float* __restrict__ out)
{
    __shared__ float xsf[2][IDIM];
    int id = blockIdx.x;
    int swz = (id & 7) * (F_GRID / 8) + (id >> 3);
    int b_blk = swz / F_NBLKN, n_blk = swz % F_NBLKN;
    int t = threadIdx.x;
    int n0 = n_blk * F_NPB + t * F_NT;
    int b0 = b_blk * F_BTILE;
    int ix[F_NT][4];
#pragma unroll
    for (int i = 0; i < 4; ++i) {
        int4 v = *reinterpret_cast<const int4*>(indices + i * NLUTS + n0);
        ix[0][i] = v.x; ix[1][i] = v.y; ix[2][i] = v.z; ix[3][i] = v.w;
    }
    float a[F_NT][16];
#pragma unroll
    for (int q = 0; q < F_NT; ++q) {
        int n = n0 + q; float p[16];
#pragma unroll
        for (int k = 0; k < 4; ++k) {
            float4 wv = *reinterpret_cast<const float4*>(w     + (size_t)n * 16 + k * 4);
            float4 cv = *reinterpret_cast<const float4*>(wcomp + (size_t)n * 16 + k * 4);
            p[15-(4*k+0)] = 1.f/(1.f+__expf(cv.x-wv.x));
            p[15-(4*k+1)] = 1.f/(1.f+__expf(cv.y-wv.y));
            p[15-(4*k+2)] = 1.f/(1.f+__expf(cv.z-wv.z));
            p[15-(4*k+3)] = 1.f/(1.f+__expf(cv.w-wv.w));
        }
#pragma unroll
        for (int s = 8; s >= 1; s >>= 1)
#pragma unroll
            for (int m = 0; m < 16; ++m)
                if ((m & s) == 0) { float t0 = p[m]; p[m] = p[m+s]; p[m+s] = t0 - p[m+s]; }
#pragma unroll
        for (int m = 0; m < 16; ++m) a[q][m] = p[m];
    }
    {
        const float* xrow = x + (size_t)b0 * IDIM;
#pragma unroll
        for (int k = 0; k < 4; ++k)
            *reinterpret_cast<float4*>(&xsf[0][(k*F_TPB+t)*4]) =
                *reinterpret_cast<const float4*>(xrow + (k*F_TPB+t)*4);
    }
    __syncthreads();
    for (int bi = 0; bi < F_BTILE; ++bi) {
        int cur = bi & 1; bool more = (bi + 1 < F_BTILE);
        float4 r[4];
        if (more) {
            const float* xrow = x + (size_t)(b0+bi+1) * IDIM;
#pragma unroll
            for (int k = 0; k < 4; ++k)
                r[k] = *reinterpret_cast<const float4*>(xrow + (k*F_TPB+t)*4);
        }
        float res[F_NT];
#pragma unroll
        for (int q = 0; q < F_NT; ++q) {
            float v0 = xsf[cur][ix[q][0]], v1 = xsf[cur][ix[q][1]];
            float v2 = xsf[cur][ix[q][2]], v3 = xsf[cur][ix[q][3]];
            float h0 = fmaf(v3,a[q][1],a[q][0]),  h1 = fmaf(v3,a[q][3],a[q][2]);
            float h2 = fmaf(v3,a[q][5],a[q][4]),  h3 = fmaf(v3,a[q][7],a[q][6]);
            float h4 = fmaf(v3,a[q][9],a[q][8]),  h5 = fmaf(v3,a[q][11],a[q][10]);
            float h6 = fmaf(v3,a[q][13],a[q][12]),h7 = fmaf(v3,a[q][15],a[q][14]);
            float g0 = fmaf(v2,h1,h0), g1 = fmaf(v2,h3,h2);
            float g2 = fmaf(v2,h5,h4), g3 = fmaf(v2,h7,h6);
            res[q] = fmaf(v0, fmaf(v1,g3,g2), fmaf(v1,g1,g0));
        }
        float4 o; o.x=res[0]; o.y=res[1]; o.z=res[2]; o.w=res[3];
        *reinterpret_cast<float4*>(out + (size_t)(b0+bi)*NLUTS + n0) = o;
        if (more) {
            int nxt = cur ^ 1;
#pragma unroll
            for (int k = 0; k < 4; ++k)
                *reinterpret_cast<float4*>(&xsf[nxt][(k*F_TPB+t)*4]) = r[k];
        }
        __syncthreads();
    }
}

extern "C" void kernel_launch(void* const* d_in, const int* in_sizes, int n_in,
                              void* d_out, int out_size, void* d_ws, size_t ws_size,
                              hipStream_t stream) {
    const float* x   = (const float*)d_in[0];
    const float* w   = (const float*)d_in[1];
    const float* wc  = (const float*)d_in[2];
    const int*   idx = (const int*)d_in[3];
    float*       out = (float*)d_out;

    if (ws_size >= (size_t)NLUTS * 16 * sizeof(float)) {
        float* cf = (float*)d_ws;
        coeff_kernel<<<dim3(NLUTS / 256), dim3(256), 0, stream>>>(w, wc, cf);
        lut_main<<<dim3(GRID), dim3(TPB), 0, stream>>>(x, cf, idx, out);
    } else {
        lut_fused<<<dim3(F_GRID), dim3(F_TPB), 0, stream>>>(x, w, wc, idx, out);
    }
}